// Round 16
// baseline (143.497 us; speedup 1.0000x reference)
//
#include <hip/hip_runtime.h>

#define S_LEN 4096
#define DMODEL 768
#define NHEAD 12
#define DHEAD 64
#define NSPLIT 4

typedef _Float16 half8 __attribute__((ext_vector_type(8)));
typedef _Float16 half4 __attribute__((ext_vector_type(4)));
typedef __fp16 fp16x2 __attribute__((ext_vector_type(2)));
typedef float f32x4 __attribute__((ext_vector_type(4)));
typedef unsigned u32x2 __attribute__((ext_vector_type(2)));

#define QSCALE 0.18033688011112042f  /* 0.125 * log2(e) */

__device__ __forceinline__ void glds16(const void* g, void* l) {
  __builtin_amdgcn_global_load_lds((const __attribute__((address_space(1))) unsigned int*)g,
                                   (__attribute__((address_space(3))) unsigned int*)l,
                                   16, 0, 0);
}
__device__ __forceinline__ float fexp2(float x) { return __builtin_amdgcn_exp2f(x); }
__device__ __forceinline__ unsigned pkh(float a, float b) {
  fp16x2 t = __builtin_amdgcn_cvt_pkrtz(a, b);
  return __builtin_bit_cast(unsigned, t);
}

// ---------------- fused fp32 -> fp16 convert for x, W_qkv, W_out ----------------
__global__ void cvt_all(const float* __restrict__ x, const float* __restrict__ w1,
                        const float* __restrict__ w2, _Float16* __restrict__ xh,
                        _Float16* __restrict__ w1h, _Float16* __restrict__ w2h) {
  int bid = blockIdx.x;
  const float* s;
  _Float16* d;
  int base;
  if (bid < 1536)      { s = x;  d = xh;  base = bid; }
  else if (bid < 2400) { s = w1; d = w1h; base = bid - 1536; }
  else                 { s = w2; d = w2h; base = bid - 2400; }
  int i = (base * 256 + threadIdx.x) * 8;
  float4 a = *(const float4*)(s + i);
  float4 b = *(const float4*)(s + i + 4);
  half8 h;
  h[0] = (_Float16)a.x; h[1] = (_Float16)a.y; h[2] = (_Float16)a.z; h[3] = (_Float16)a.w;
  h[4] = (_Float16)b.x; h[5] = (_Float16)b.y; h[6] = (_Float16)b.z; h[7] = (_Float16)b.w;
  *(half8*)(d + i) = h;
}

// ---------------- NT GEMM: C[M,N] = A[M,K] * B[N,K]^T + bias (R10-proven, 128x128) ----------------
// Single-barrier triple-buffer pipeline (stage-distance 2, steady vmcnt(4)).
// NOTE: 64x128 tiles regressed (R13). NOTE: fusing combine into this regressed (R15,
// 192-block kernel has no TLP to hide added latency). Keep pure.
template<int EPI, int NTN>
__global__ __launch_bounds__(256, 2)
void gemm_nt(const _Float16* __restrict__ A, const _Float16* __restrict__ Bm,
             const float* __restrict__ bias, int M, int N, int K,
             _Float16* __restrict__ qb, _Float16* __restrict__ kb, _Float16* __restrict__ vb,
             float* __restrict__ outp) {
  __shared__ _Float16 Ash[3][128 * 32];
  __shared__ _Float16 Bsh[3][128 * 32];
  const int tid = threadIdx.x, lane = tid & 63, wv = tid >> 6;
  const int wr = wv >> 1, wc = wv & 1;
  const int l15 = lane & 15, lg = lane >> 4;
  const int nwg = gridDim.x;
  const int gid = (blockIdx.x & 7) * (nwg >> 3) + (blockIdx.x >> 3);
  const int tm = (gid / NTN) * 128, tn = (gid % NTN) * 128;

  f32x4 acc[4][4] = {};

  auto stage = [&](int kt, int b) {
#pragma unroll
    for (int is = 0; is < 2; is++) {
      int c = is * 256 + tid;
      int r = c >> 2, cc = c & 3;
      glds16(A + (size_t)(tm + r) * K + kt * 32 + cc * 8, &Ash[b][(is * 256 + wv * 64) * 8]);
    }
#pragma unroll
    for (int is = 0; is < 2; is++) {
      int c = is * 256 + tid;
      int r = c >> 2, cc = c & 3;
      glds16(Bm + (size_t)(tn + r) * K + kt * 32 + cc * 8, &Bsh[b][(is * 256 + wv * 64) * 8]);
    }
  };

  const int nk = K >> 5;    // 24 for K=768
  stage(0, 0);
  stage(1, 1);

  int cur = 0;
  for (int kt = 0; kt < nk; kt++) {
    if (kt < nk - 1) asm volatile("s_waitcnt vmcnt(4)" ::: "memory");
    else             asm volatile("s_waitcnt vmcnt(0)" ::: "memory");
    __builtin_amdgcn_sched_barrier(0);
    __builtin_amdgcn_s_barrier();

    half8 af[4], bf[4];
#pragma unroll
    for (int m = 0; m < 4; m++)
      af[m] = *(const half8*)&Ash[cur][(wr * 64 + m * 16 + l15) * 32 + lg * 8];
#pragma unroll
    for (int n = 0; n < 4; n++)
      bf[n] = *(const half8*)&Bsh[cur][(wc * 64 + n * 16 + l15) * 32 + lg * 8];
    __builtin_amdgcn_s_setprio(1);
#pragma unroll
    for (int m = 0; m < 4; m++)
#pragma unroll
      for (int n = 0; n < 4; n++)
        acc[m][n] = __builtin_amdgcn_mfma_f32_16x16x32_f16(af[m], bf[n], acc[m][n], 0, 0, 0);
    __builtin_amdgcn_s_setprio(0);

    if (kt < nk - 2) {
      int nb = cur + 2; if (nb >= 3) nb -= 3;
      stage(kt + 2, nb);
    }
    cur = (cur == 2) ? 0 : cur + 1;
  }

#pragma unroll
  for (int m = 0; m < 4; m++) {
#pragma unroll
    for (int n = 0; n < 4; n++) {
#pragma unroll
      for (int j = 0; j < 4; j++) {
        int gr = tm + wr * 64 + m * 16 + lg * 4 + j;
        int gc = tn + wc * 64 + n * 16 + l15;
        float val = acc[m][n][j] + bias[gc];
        if (EPI == 0) {
          int which = gc / 768;
          int dmcol = gc % 768;
          int head = dmcol >> 6, dh = dmcol & 63;
          if (which == 0) {
            qb[((size_t)head * S_LEN + gr) * DHEAD + dh] = (_Float16)(val * QSCALE);
          } else if (which == 1) {
            kb[((size_t)head * S_LEN + gr) * DHEAD + dh] = (_Float16)val;
          } else {
            vb[((size_t)head * DHEAD + dh) * S_LEN + gr] = (_Float16)val;  // V transposed
          }
        } else {
          outp[(size_t)gr * N + gc] = val;
        }
      }
    }
  }
}

// ---------------- attention: 4-way split-K flash, deferred-PV software pipeline ----------------
// R10 barrier/buffer structure (triple-buffer, single barrier, steady vmcnt(4)) with the
// per-wave chain broken (T15): PV of tile t-1 runs from REGISTERS (packed P `pa`, V frags
// `vfp`) right after QK(t) issues — independent MFMAs keep the matrix pipe fed while
// exp2/pack(t) run on VALU. V frags for tile t are ds_read at body end (1 iter of cover).
// p' = exp2(s-6): scale folded into acc init, cancels in O/l.
// NOTE: launch_bounds min-waves MUST stay at 3 — 4 spills accumulators (R3: +240 MB HBM).
// NOTE: do NOT pair q-tiles (R11 spill). NSPLIT=8 (R12) / NSPLIT=2 (R14) both worse.
__global__ __launch_bounds__(256, 3)
void attn_kernel(const _Float16* __restrict__ Q, const _Float16* __restrict__ K,
                 const _Float16* __restrict__ Vt,
                 _Float16* __restrict__ Oph, float* __restrict__ Lp) {
  __shared__ _Float16 Ksh[3][64 * 64];   // [key][d], 16B chunks swizzled by key&7
  __shared__ _Float16 Vsh[3][64 * 64];   // [d][key], 16B chunks swizzled by d&7

  const int tid = threadIdx.x, lane = tid & 63, wv = tid >> 6;
  const int l15 = lane & 15, lg = lane >> 4;
  const int flat = blockIdx.x;
  const int gid = (flat & 7) * 192 + (flat >> 3);
  const int h = gid >> 7;
  const int qtr = gid & 31, sp = (gid >> 5) & 3;
  const int qt = (qtr & 1) ? (31 - (qtr >> 1)) : (qtr >> 1);   // 0,31,1,30,... balance
  const int qg0 = qt * 128 + wv * 32;

  const _Float16* Qh = Q + (size_t)h * S_LEN * DHEAD;
  const _Float16* Kh = K + (size_t)h * S_LEN * DHEAD;
  const _Float16* Vh = Vt + (size_t)h * DHEAD * S_LEN;

  half8 qf[2][2];
#pragma unroll
  for (int i = 0; i < 2; i++)
#pragma unroll
    for (int ks = 0; ks < 2; ks++)
      qf[i][ks] = *(const half8*)(Qh + (size_t)(qg0 + i * 16 + l15) * DHEAD + ks * 32 + lg * 8);

  f32x4 lacc[2] = {};
  f32x4 Oa[2][4] = {};
  half4 pa0[4], pa1[4];    // packed P of tile t-1 (carried in regs)
  half4 vfp[4][4];         // V fragments [kf][df] of tile t-1 (carried in regs)
  bool pvP = false;

  auto stage = [&](int t, int b) {
    const int k0 = (NSPLIT * t + sp) * 64;
#pragma unroll
    for (int is = 0; is < 2; is++) {
      int c = is * 256 + tid;
      int r = c >> 3, cc = c & 7;
      glds16(Kh + (size_t)(k0 + r) * DHEAD + ((cc ^ (r & 7)) * 8),
             &Ksh[b][(is * 256 + wv * 64) * 8]);
    }
#pragma unroll
    for (int is = 0; is < 2; is++) {
      int c = is * 256 + tid;
      int d = c >> 3, cc = c & 7;
      glds16(Vh + (size_t)d * S_LEN + k0 + ((cc ^ (d & 7)) * 8),
             &Vsh[b][(is * 256 + wv * 64) * 8]);
    }
  };

  stage(0, 0);
  stage(1, 1);

  const int NT = S_LEN / (64 * NSPLIT);   // 16 tiles per split
  int cur = 0;
  for (int t = 0; t < NT; t++) {
    const int k0g = (NSPLIT * t + sp) * 64;

    if (t < NT - 1) asm volatile("s_waitcnt vmcnt(4)" ::: "memory");
    else            asm volatile("s_waitcnt vmcnt(0)" ::: "memory");
    __builtin_amdgcn_sched_barrier(0);
    __builtin_amdgcn_s_barrier();   // all waves' tile-t loads complete

    // ---- QK(t): S^T = K Q^T (acc pre-biased to -6); q = l15, key = kf*16+lg*4+j ----
    f32x4 sa[2][4];
#pragma unroll
    for (int i = 0; i < 2; i++)
#pragma unroll
      for (int kf = 0; kf < 4; kf++)
#pragma unroll
        for (int j = 0; j < 4; j++) sa[i][kf][j] = -6.f;
    __builtin_amdgcn_s_setprio(1);
#pragma unroll
    for (int ks = 0; ks < 2; ks++) {
#pragma unroll
      for (int kf = 0; kf < 4; kf++) {
        int key = kf * 16 + l15;
        half8 kfr = *(const half8*)&Ksh[cur][key * 64 + (((ks * 4 + lg) ^ (key & 7)) * 8)];
#pragma unroll
        for (int i = 0; i < 2; i++)
          sa[i][kf] = __builtin_amdgcn_mfma_f32_16x16x32_f16(kfr, qf[i][ks], sa[i][kf], 0, 0, 0);
      }
    }

    // ---- PV(t-1): fully register-resident, independent of QK(t) ----
    if (pvP) {
#pragma unroll
      for (int kf = 0; kf < 4; kf++)
#pragma unroll
        for (int df = 0; df < 4; df++) {
          Oa[0][df] = __builtin_amdgcn_mfma_f32_16x16x16f16(vfp[kf][df], pa0[kf], Oa[0][df], 0, 0, 0);
          Oa[1][df] = __builtin_amdgcn_mfma_f32_16x16x16f16(vfp[kf][df], pa1[kf], Oa[1][df], 0, 0, 0);
        }
    }
    __builtin_amdgcn_s_setprio(0);

    // ---- p' = exp2(s-6); per-lane partial row sums ----
#pragma unroll
    for (int i = 0; i < 2; i++)
#pragma unroll
      for (int kf = 0; kf < 4; kf++) {
#pragma unroll
        for (int j = 0; j < 4; j++) sa[i][kf][j] = fexp2(sa[i][kf][j]);
        lacc[i] += sa[i][kf];
      }

    // ---- mask + pack P(t), and load V(t) fragments into regs for next iteration ----
    const bool pvNow = (k0g <= qg0 + 31);
    if (pvNow) {
      if (k0g + 63 > qg0) {   // diagonal tiles only
#pragma unroll
        for (int i = 0; i < 2; i++) {
          int qg = qg0 + i * 16 + l15;
#pragma unroll
          for (int kf = 0; kf < 4; kf++) {
            int kb = k0g + kf * 16 + lg * 4;
#pragma unroll
            for (int j = 0; j < 4; j++)
              if (kb + j > qg) sa[i][kf][j] = 0.f;
          }
        }
      }
#pragma unroll
      for (int kf = 0; kf < 4; kf++) {
        pa0[kf] = __builtin_bit_cast(half4,
            (u32x2){pkh(sa[0][kf][0], sa[0][kf][1]), pkh(sa[0][kf][2], sa[0][kf][3])});
        pa1[kf] = __builtin_bit_cast(half4,
            (u32x2){pkh(sa[1][kf][0], sa[1][kf][1]), pkh(sa[1][kf][2], sa[1][kf][3])});
      }
#pragma unroll
      for (int kf = 0; kf < 4; kf++)
#pragma unroll
        for (int df = 0; df < 4; df++) {
          int d = df * 16 + l15;
          vfp[kf][df] = *(const half4*)&Vsh[cur][d * 64 + (((kf * 2 + (lg >> 1)) ^ (d & 7)) * 8) + (lg & 1) * 4];
        }
    }
    pvP = pvNow;

    if (t < NT - 2) {
      int nb = cur + 2; if (nb >= 3) nb -= 3;
      stage(t + 2, nb);
    }
    cur = (cur == 2) ? 0 : cur + 1;
  }

  // ---- drain: final PV(NT-1) ----
  if (pvP) {
    __builtin_amdgcn_s_setprio(1);
#pragma unroll
    for (int kf = 0; kf < 4; kf++)
#pragma unroll
      for (int df = 0; df < 4; df++) {
        Oa[0][df] = __builtin_amdgcn_mfma_f32_16x16x16f16(vfp[kf][df], pa0[kf], Oa[0][df], 0, 0, 0);
        Oa[1][df] = __builtin_amdgcn_mfma_f32_16x16x16f16(vfp[kf][df], pa1[kf], Oa[1][df], 0, 0, 0);
      }
    __builtin_amdgcn_s_setprio(0);
  }

  // ---- epilogue: partial O (f16) + row sums l (f32) ----
  const size_t obase = (size_t)(sp * NHEAD + h) * S_LEN * DHEAD;
#pragma unroll
  for (int i = 0; i < 2; i++) {
    int qg = qg0 + i * 16 + l15;
#pragma unroll
    for (int df = 0; df < 4; df++) {
      half4 ov;
#pragma unroll
      for (int j = 0; j < 4; j++) ov[j] = (_Float16)Oa[i][df][j];
      *(half4*)&Oph[obase + (size_t)qg * DHEAD + df * 16 + lg * 4] = ov;
    }
    float ls = lacc[i][0] + lacc[i][1] + lacc[i][2] + lacc[i][3];
    ls += __shfl_xor(ls, 16);
    ls += __shfl_xor(ls, 32);
    if (lg == 0) Lp[(size_t)(sp * NHEAD + h) * S_LEN + qg] = ls;
  }
}

// ---------------- combine the four k-splits: Y = (ΣO)/(Σl) ----------------
__global__ void combine(const _Float16* __restrict__ Oph, const float* __restrict__ Lp,
                        _Float16* __restrict__ Y) {
  int idx = blockIdx.x * 256 + threadIdx.x;
  int d = (idx & 7) * 8;
  int qh = idx >> 3;
  int q = qh & (S_LEN - 1);
  int h = qh >> 12;
  float l = 0.f;
#pragma unroll
  for (int s = 0; s < NSPLIT; s++) l += Lp[(size_t)(s * NHEAD + h) * S_LEN + q];
  float inv = 1.f / l;
  float o[8] = {};
#pragma unroll
  for (int s = 0; s < NSPLIT; s++) {
    half8 v = *(const half8*)&Oph[((size_t)(s * NHEAD + h) * S_LEN + q) * DHEAD + d];
#pragma unroll
    for (int j = 0; j < 8; j++) o[j] += (float)v[j];
  }
  half8 out;
#pragma unroll
  for (int j = 0; j < 8; j++) out[j] = (_Float16)(o[j] * inv);
  *(half8*)(Y + (size_t)q * DMODEL + h * 64 + d) = out;
}

extern "C" void kernel_launch(void* const* d_in, const int* in_sizes, int n_in,
                              void* d_out, int out_size, void* d_ws, size_t ws_size,
                              hipStream_t stream) {
  const float* x    = (const float*)d_in[0];
  const float* Wqkv = (const float*)d_in[1];
  const float* bqkv = (const float*)d_in[2];
  const float* Wout = (const float*)d_in[3];
  const float* bout = (const float*)d_in[4];
  float* out = (float*)d_out;

  size_t off = 0;
  auto alloc = [&](size_t bytes) {
    void* p = (char*)d_ws + off;
    off += (bytes + 255) & ~(size_t)255;
    return p;
  };
  _Float16* xh    = (_Float16*)alloc((size_t)S_LEN * DMODEL * 2);
  _Float16* wqkvh = (_Float16*)alloc((size_t)3 * DMODEL * DMODEL * 2);
  _Float16* wouth = (_Float16*)alloc((size_t)DMODEL * DMODEL * 2);
  _Float16* Qb    = (_Float16*)alloc((size_t)NHEAD * S_LEN * DHEAD * 2);
  _Float16* Kb    = (_Float16*)alloc((size_t)NHEAD * S_LEN * DHEAD * 2);
  _Float16* Vb    = (_Float16*)alloc((size_t)NHEAD * S_LEN * DHEAD * 2);  // transposed [H][64][S]
  _Float16* Yb    = (_Float16*)alloc((size_t)S_LEN * DMODEL * 2);
  _Float16* Oph   = (_Float16*)alloc((size_t)NSPLIT * NHEAD * S_LEN * DHEAD * 2);
  float*    Lpb   = (float*)alloc((size_t)NSPLIT * NHEAD * S_LEN * 4);

  cvt_all<<<2688, 256, 0, stream>>>(x, Wqkv, Wout, xh, wqkvh, wouth);

  gemm_nt<0, 18><<<576, 256, 0, stream>>>(xh, wqkvh, bqkv, S_LEN, 3 * DMODEL, DMODEL,
                                          Qb, Kb, Vb, nullptr);

  attn_kernel<<<32 * NSPLIT * NHEAD, 256, 0, stream>>>(Qb, Kb, Vb, Oph, Lpb);

  combine<<<(NHEAD * S_LEN * 8) / 256, 256, 0, stream>>>(Oph, Lpb, Yb);

  gemm_nt<1, 6><<<192, 256, 0, stream>>>(Yb, wouth, bout, S_LEN, DMODEL, DMODEL,
                                         nullptr, nullptr, nullptr, out);
}

// Round 17
// 124.162 us; speedup vs baseline: 1.1557x; 1.1557x over previous
//
#include <hip/hip_runtime.h>

#define S_LEN 4096
#define DMODEL 768
#define NHEAD 12
#define DHEAD 64
#define NSPLIT 4

typedef _Float16 half8 __attribute__((ext_vector_type(8)));
typedef _Float16 half4 __attribute__((ext_vector_type(4)));
typedef __fp16 fp16x2 __attribute__((ext_vector_type(2)));
typedef float f32x4 __attribute__((ext_vector_type(4)));
typedef unsigned u32x2 __attribute__((ext_vector_type(2)));

#define QSCALE 0.18033688011112042f  /* 0.125 * log2(e) */

__device__ __forceinline__ void glds16(const void* g, void* l) {
  __builtin_amdgcn_global_load_lds((const __attribute__((address_space(1))) unsigned int*)g,
                                   (__attribute__((address_space(3))) unsigned int*)l,
                                   16, 0, 0);
}
__device__ __forceinline__ float fexp2(float x) { return __builtin_amdgcn_exp2f(x); }
__device__ __forceinline__ unsigned pkh(float a, float b) {
  fp16x2 t = __builtin_amdgcn_cvt_pkrtz(a, b);
  return __builtin_bit_cast(unsigned, t);
}

// ---------------- fused fp32 -> fp16 convert for x, W_qkv, W_out ----------------
__global__ void cvt_all(const float* __restrict__ x, const float* __restrict__ w1,
                        const float* __restrict__ w2, _Float16* __restrict__ xh,
                        _Float16* __restrict__ w1h, _Float16* __restrict__ w2h) {
  int bid = blockIdx.x;
  const float* s;
  _Float16* d;
  int base;
  if (bid < 1536)      { s = x;  d = xh;  base = bid; }
  else if (bid < 2400) { s = w1; d = w1h; base = bid - 1536; }
  else                 { s = w2; d = w2h; base = bid - 2400; }
  int i = (base * 256 + threadIdx.x) * 8;
  float4 a = *(const float4*)(s + i);
  float4 b = *(const float4*)(s + i + 4);
  half8 h;
  h[0] = (_Float16)a.x; h[1] = (_Float16)a.y; h[2] = (_Float16)a.z; h[3] = (_Float16)a.w;
  h[4] = (_Float16)b.x; h[5] = (_Float16)b.y; h[6] = (_Float16)b.z; h[7] = (_Float16)b.w;
  *(half8*)(d + i) = h;
}

// ---------------- NT GEMM: C[M,N] = A[M,K] * B[N,K]^T + bias (R10-proven, 128x128) ----------------
// Single-barrier triple-buffer pipeline: stage-distance 2, one s_barrier per K-step,
// steady vmcnt(4). Overwrite target (kt+2)%3 != read buffer kt%3 != in-flight (kt+1)%3;
// the top-of-step barrier bounds inter-wave skew to one step -> race-free.
// NOTE: 64x128 tiles regressed (R13: staging-instr/MFMA 1.9x worse). NOTE: fusing combine
// into gemm_out regressed (R15: 192-block kernel has no TLP to hide added latency).
template<int EPI, int NTN>
__global__ __launch_bounds__(256, 2)
void gemm_nt(const _Float16* __restrict__ A, const _Float16* __restrict__ Bm,
             const float* __restrict__ bias, int M, int N, int K,
             _Float16* __restrict__ qb, _Float16* __restrict__ kb, _Float16* __restrict__ vb,
             float* __restrict__ outp) {
  __shared__ _Float16 Ash[3][128 * 32];
  __shared__ _Float16 Bsh[3][128 * 32];
  const int tid = threadIdx.x, lane = tid & 63, wv = tid >> 6;
  const int wr = wv >> 1, wc = wv & 1;
  const int l15 = lane & 15, lg = lane >> 4;
  const int nwg = gridDim.x;
  const int gid = (blockIdx.x & 7) * (nwg >> 3) + (blockIdx.x >> 3);
  const int tm = (gid / NTN) * 128, tn = (gid % NTN) * 128;

  f32x4 acc[4][4] = {};

  auto stage = [&](int kt, int b) {
#pragma unroll
    for (int is = 0; is < 2; is++) {
      int c = is * 256 + tid;
      int r = c >> 2, cc = c & 3;
      glds16(A + (size_t)(tm + r) * K + kt * 32 + cc * 8, &Ash[b][(is * 256 + wv * 64) * 8]);
    }
#pragma unroll
    for (int is = 0; is < 2; is++) {
      int c = is * 256 + tid;
      int r = c >> 2, cc = c & 3;
      glds16(Bm + (size_t)(tn + r) * K + kt * 32 + cc * 8, &Bsh[b][(is * 256 + wv * 64) * 8]);
    }
  };

  const int nk = K >> 5;    // 24 for K=768
  stage(0, 0);
  stage(1, 1);

  int cur = 0;
  for (int kt = 0; kt < nk; kt++) {
    if (kt < nk - 1) asm volatile("s_waitcnt vmcnt(4)" ::: "memory");
    else             asm volatile("s_waitcnt vmcnt(0)" ::: "memory");
    __builtin_amdgcn_sched_barrier(0);
    __builtin_amdgcn_s_barrier();

    half8 af[4], bf[4];
#pragma unroll
    for (int m = 0; m < 4; m++)
      af[m] = *(const half8*)&Ash[cur][(wr * 64 + m * 16 + l15) * 32 + lg * 8];
#pragma unroll
    for (int n = 0; n < 4; n++)
      bf[n] = *(const half8*)&Bsh[cur][(wc * 64 + n * 16 + l15) * 32 + lg * 8];
    __builtin_amdgcn_s_setprio(1);
#pragma unroll
    for (int m = 0; m < 4; m++)
#pragma unroll
      for (int n = 0; n < 4; n++)
        acc[m][n] = __builtin_amdgcn_mfma_f32_16x16x32_f16(af[m], bf[n], acc[m][n], 0, 0, 0);
    __builtin_amdgcn_s_setprio(0);

    if (kt < nk - 2) {
      int nb = cur + 2; if (nb >= 3) nb -= 3;
      stage(kt + 2, nb);
    }
    cur = (cur == 2) ? 0 : cur + 1;
  }

#pragma unroll
  for (int m = 0; m < 4; m++) {
#pragma unroll
    for (int n = 0; n < 4; n++) {
#pragma unroll
      for (int j = 0; j < 4; j++) {
        int gr = tm + wr * 64 + m * 16 + lg * 4 + j;
        int gc = tn + wc * 64 + n * 16 + l15;
        float val = acc[m][n][j] + bias[gc];
        if (EPI == 0) {
          int which = gc / 768;
          int dmcol = gc % 768;
          int head = dmcol >> 6, dh = dmcol & 63;
          if (which == 0) {
            qb[((size_t)head * S_LEN + gr) * DHEAD + dh] = (_Float16)(val * QSCALE);
          } else if (which == 1) {
            kb[((size_t)head * S_LEN + gr) * DHEAD + dh] = (_Float16)val;
          } else {
            vb[((size_t)head * DHEAD + dh) * S_LEN + gr] = (_Float16)val;  // V transposed
          }
        } else {
          outp[(size_t)gr * N + gc] = val;
        }
      }
    }
  }
}

// ---------------- attention (R10-proven: 4-way split-K flash, no-max softmax) ----------------
// Single-barrier triple-buffer (stage-distance 2, steady vmcnt(4)); XCD-chunked grid 1536
// (192/XCD); work-balanced qt (0,31,1,30,...). p' = exp2(s-6), scale cancels in O/l.
// P never leaves registers (QK 16x16x32 C-layout == PV 16x16x16 B-layout).
// REGISTER-PRESSURE WALL (keep these notes):
//  - launch_bounds min-waves MUST stay 3 — 4 spills accumulators (R3: +240 MB HBM traffic).
//  - do NOT pair q-tiles per block (R11: 2x live state -> spill, 4x slower).
//  - do NOT carry P/V fragments across iterations (R16 deferred-PV: +48 live VGPR -> spill).
//  - NSPLIT=8 (R12) and NSPLIT=2 (R14) both measured worse; 32x32 MFMA path (R8) worse.
__global__ __launch_bounds__(256, 3)
void attn_kernel(const _Float16* __restrict__ Q, const _Float16* __restrict__ K,
                 const _Float16* __restrict__ Vt,
                 _Float16* __restrict__ Oph, float* __restrict__ Lp) {
  __shared__ _Float16 Ksh[3][64 * 64];   // [key][d], 16B chunks swizzled by key&7
  __shared__ _Float16 Vsh[3][64 * 64];   // [d][key], 16B chunks swizzled by d&7

  const int tid = threadIdx.x, lane = tid & 63, wv = tid >> 6;
  const int l15 = lane & 15, lg = lane >> 4;
  const int flat = blockIdx.x;
  const int gid = (flat & 7) * 192 + (flat >> 3);
  const int h = gid >> 7;
  const int qtr = gid & 31, sp = (gid >> 5) & 3;
  const int qt = (qtr & 1) ? (31 - (qtr >> 1)) : (qtr >> 1);   // 0,31,1,30,... balance
  const int qg0 = qt * 128 + wv * 32;

  const _Float16* Qh = Q + (size_t)h * S_LEN * DHEAD;
  const _Float16* Kh = K + (size_t)h * S_LEN * DHEAD;
  const _Float16* Vh = Vt + (size_t)h * DHEAD * S_LEN;

  half8 qf[2][2];
#pragma unroll
  for (int i = 0; i < 2; i++)
#pragma unroll
    for (int ks = 0; ks < 2; ks++)
      qf[i][ks] = *(const half8*)(Qh + (size_t)(qg0 + i * 16 + l15) * DHEAD + ks * 32 + lg * 8);

  f32x4 lacc[2] = {};
  f32x4 Oa[2][4] = {};

  auto stage = [&](int t, int b) {
    const int k0 = (NSPLIT * t + sp) * 64;
#pragma unroll
    for (int is = 0; is < 2; is++) {
      int c = is * 256 + tid;
      int r = c >> 3, cc = c & 7;
      glds16(Kh + (size_t)(k0 + r) * DHEAD + ((cc ^ (r & 7)) * 8),
             &Ksh[b][(is * 256 + wv * 64) * 8]);
    }
#pragma unroll
    for (int is = 0; is < 2; is++) {
      int c = is * 256 + tid;
      int d = c >> 3, cc = c & 7;
      glds16(Vh + (size_t)d * S_LEN + k0 + ((cc ^ (d & 7)) * 8),
             &Vsh[b][(is * 256 + wv * 64) * 8]);
    }
  };

  stage(0, 0);
  stage(1, 1);

  const int NT = S_LEN / (64 * NSPLIT);   // 16 tiles per split
  int cur = 0;
  for (int t = 0; t < NT; t++) {
    const int k0g = (NSPLIT * t + sp) * 64;

    if (t < NT - 1) asm volatile("s_waitcnt vmcnt(4)" ::: "memory");
    else            asm volatile("s_waitcnt vmcnt(0)" ::: "memory");
    __builtin_amdgcn_sched_barrier(0);
    __builtin_amdgcn_s_barrier();   // all waves' tile-t loads complete

    // ---- S^T = K Q^T (acc pre-biased to -6): per-lane q = l15, key = kf*16+lg*4+j ----
    f32x4 sa[2][4];
#pragma unroll
    for (int i = 0; i < 2; i++)
#pragma unroll
      for (int kf = 0; kf < 4; kf++)
#pragma unroll
        for (int j = 0; j < 4; j++) sa[i][kf][j] = -6.f;
    __builtin_amdgcn_s_setprio(1);
#pragma unroll
    for (int ks = 0; ks < 2; ks++) {
#pragma unroll
      for (int kf = 0; kf < 4; kf++) {
        int key = kf * 16 + l15;
        half8 kfr = *(const half8*)&Ksh[cur][key * 64 + (((ks * 4 + lg) ^ (key & 7)) * 8)];
#pragma unroll
        for (int i = 0; i < 2; i++)
          sa[i][kf] = __builtin_amdgcn_mfma_f32_16x16x32_f16(kfr, qf[i][ks], sa[i][kf], 0, 0, 0);
      }
    }
    __builtin_amdgcn_s_setprio(0);

    // ---- p' = exp2(s-6); per-lane partial row sums (scaled l, cancels in O/l) ----
#pragma unroll
    for (int i = 0; i < 2; i++)
#pragma unroll
      for (int kf = 0; kf < 4; kf++) {
#pragma unroll
        for (int j = 0; j < 4; j++) sa[i][kf][j] = fexp2(sa[i][kf][j]);
        lacc[i] += sa[i][kf];
      }

    // ---- PV with post-softmax causal mask (registers only; skip future tiles) ----
    if (k0g <= qg0 + 31) {
      if (k0g + 63 > qg0) {   // diagonal tiles only
#pragma unroll
        for (int i = 0; i < 2; i++) {
          int qg = qg0 + i * 16 + l15;
#pragma unroll
          for (int kf = 0; kf < 4; kf++) {
            int kb = k0g + kf * 16 + lg * 4;
#pragma unroll
            for (int j = 0; j < 4; j++)
              if (kb + j > qg) sa[i][kf][j] = 0.f;
          }
        }
      }
      __builtin_amdgcn_s_setprio(1);
#pragma unroll
      for (int kf = 0; kf < 4; kf++) {
        half4 pa0 = __builtin_bit_cast(half4,
            (u32x2){pkh(sa[0][kf][0], sa[0][kf][1]), pkh(sa[0][kf][2], sa[0][kf][3])});
        half4 pa1 = __builtin_bit_cast(half4,
            (u32x2){pkh(sa[1][kf][0], sa[1][kf][1]), pkh(sa[1][kf][2], sa[1][kf][3])});
#pragma unroll
        for (int df = 0; df < 4; df++) {
          int d = df * 16 + l15;
          half4 vf = *(const half4*)&Vsh[cur][d * 64 + (((kf * 2 + (lg >> 1)) ^ (d & 7)) * 8) + (lg & 1) * 4];
          Oa[0][df] = __builtin_amdgcn_mfma_f32_16x16x16f16(vf, pa0, Oa[0][df], 0, 0, 0);
          Oa[1][df] = __builtin_amdgcn_mfma_f32_16x16x16f16(vf, pa1, Oa[1][df], 0, 0, 0);
        }
      }
      __builtin_amdgcn_s_setprio(0);
    }

    if (t < NT - 2) {
      int nb = cur + 2; if (nb >= 3) nb -= 3;
      stage(t + 2, nb);
    }
    cur = (cur == 2) ? 0 : cur + 1;
  }

  // ---- epilogue: partial O (f16) + row sums l (f32) ----
  const size_t obase = (size_t)(sp * NHEAD + h) * S_LEN * DHEAD;
#pragma unroll
  for (int i = 0; i < 2; i++) {
    int qg = qg0 + i * 16 + l15;
#pragma unroll
    for (int df = 0; df < 4; df++) {
      half4 ov;
#pragma unroll
      for (int j = 0; j < 4; j++) ov[j] = (_Float16)Oa[i][df][j];
      *(half4*)&Oph[obase + (size_t)qg * DHEAD + df * 16 + lg * 4] = ov;
    }
    float ls = lacc[i][0] + lacc[i][1] + lacc[i][2] + lacc[i][3];
    ls += __shfl_xor(ls, 16);
    ls += __shfl_xor(ls, 32);
    if (lg == 0) Lp[(size_t)(sp * NHEAD + h) * S_LEN + qg] = ls;
  }
}

// ---------------- combine the four k-splits: Y = (ΣO)/(Σl) ----------------
__global__ void combine(const _Float16* __restrict__ Oph, const float* __restrict__ Lp,
                        _Float16* __restrict__ Y) {
  int idx = blockIdx.x * 256 + threadIdx.x;
  int d = (idx & 7) * 8;
  int qh = idx >> 3;
  int q = qh & (S_LEN - 1);
  int h = qh >> 12;
  float l = 0.f;
#pragma unroll
  for (int s = 0; s < NSPLIT; s++) l += Lp[(size_t)(s * NHEAD + h) * S_LEN + q];
  float inv = 1.f / l;
  float o[8] = {};
#pragma unroll
  for (int s = 0; s < NSPLIT; s++) {
    half8 v = *(const half8*)&Oph[((size_t)(s * NHEAD + h) * S_LEN + q) * DHEAD + d];
#pragma unroll
    for (int j = 0; j < 8; j++) o[j] += (float)v[j];
  }
  half8 out;
#pragma unroll
  for (int j = 0; j < 8; j++) out[j] = (_Float16)(o[j] * inv);
  *(half8*)(Y + (size_t)q * DMODEL + h * 64 + d) = out;
}

extern "C" void kernel_launch(void* const* d_in, const int* in_sizes, int n_in,
                              void* d_out, int out_size, void* d_ws, size_t ws_size,
                              hipStream_t stream) {
  const float* x    = (const float*)d_in[0];
  const float* Wqkv = (const float*)d_in[1];
  const float* bqkv = (const float*)d_in[2];
  const float* Wout = (const float*)d_in[3];
  const float* bout = (const float*)d_in[4];
  float* out = (float*)d_out;

  size_t off = 0;
  auto alloc = [&](size_t bytes) {
    void* p = (char*)d_ws + off;
    off += (bytes + 255) & ~(size_t)255;
    return p;
  };
  _Float16* xh    = (_Float16*)alloc((size_t)S_LEN * DMODEL * 2);
  _Float16* wqkvh = (_Float16*)alloc((size_t)3 * DMODEL * DMODEL * 2);
  _Float16* wouth = (_Float16*)alloc((size_t)DMODEL * DMODEL * 2);
  _Float16* Qb    = (_Float16*)alloc((size_t)NHEAD * S_LEN * DHEAD * 2);
  _Float16* Kb    = (_Float16*)alloc((size_t)NHEAD * S_LEN * DHEAD * 2);
  _Float16* Vb    = (_Float16*)alloc((size_t)NHEAD * S_LEN * DHEAD * 2);  // transposed [H][64][S]
  _Float16* Yb    = (_Float16*)alloc((size_t)S_LEN * DMODEL * 2);
  _Float16* Oph   = (_Float16*)alloc((size_t)NSPLIT * NHEAD * S_LEN * DHEAD * 2);
  float*    Lpb   = (float*)alloc((size_t)NSPLIT * NHEAD * S_LEN * 4);

  cvt_all<<<2688, 256, 0, stream>>>(x, Wqkv, Wout, xh, wqkvh, wouth);

  gemm_nt<0, 18><<<576, 256, 0, stream>>>(xh, wqkvh, bqkv, S_LEN, 3 * DMODEL, DMODEL,
                                          Qb, Kb, Vb, nullptr);

  attn_kernel<<<32 * NSPLIT * NHEAD, 256, 0, stream>>>(Qb, Kb, Vb, Oph, Lpb);

  combine<<<(NHEAD * S_LEN * 8) / 256, 256, 0, stream>>>(Oph, Lpb, Yb);

  gemm_nt<1, 6><<<192, 256, 0, stream>>>(Yb, wouth, bout, S_LEN, DMODEL, DMODEL,
                                         nullptr, nullptr, nullptr, out);
}